// Round 16
// baseline (307.848 us; speedup 1.0000x reference)
//
#include <hip/hip_runtime.h>
#include <math.h>

constexpr int N_ = 1024;
constexpr int H_ = 128;
constexpr int D_ = 256;
constexpr int L_ = 3;
constexpr int NT_ = N_ / 32;           // j-tiles per block
constexpr int ROWB_ = H_ * 2;          // bytes per bf16 row (lut / prj)
constexpr int TILEB_ = 32 * ROWB_;     // bytes per j-tile of prj
constexpr float EPS_ = 1e-5f;
constexpr float LOG2E_ = 1.44269504f;
constexpr int KLUT_ = 8192;
constexpr float DMAX_ = 40.0f;
constexpr float TSCALE_ = (KLUT_ - 1) / DMAX_;
constexpr float TMAX_ = (float)(KLUT_ - 1) - 0.001f;

// odd deg-7 fit of (sigmoid(x)-0.5)/x in u=x^2 over [0,16] (Chebyshev nodes);
// |sigmoid err| <~ 2e-3 on [-4,4]
constexpr float PC0_ = 0.2487467f;
constexpr float PC1_ = -0.0181606f;
constexpr float PC2_ = 0.0010210f;
constexpr float PC3_ = -2.4300e-5f;

typedef float v2f __attribute__((ext_vector_type(2)));
typedef unsigned short ushort16;

__device__ __forceinline__ float fsig(float v) {            // sigmoid (trans path)
    float e = __builtin_amdgcn_exp2f(v * -LOG2E_);
    return __builtin_amdgcn_rcpf(1.0f + e);
}

template <int CTRL>
__device__ __forceinline__ float rowadd(float x) {
    int y = __builtin_amdgcn_update_dpp(0, __float_as_int(x), CTRL, 0xF, 0xF, true);
    return x + __int_as_float(y);
}
__device__ __forceinline__ float rowreduce16(float x) {
    x = rowadd<0x128>(x);   // row_ror:8
    x = rowadd<0x124>(x);   // row_ror:4
    x = rowadd<0x122>(x);   // row_ror:2
    x = rowadd<0x121>(x);   // row_ror:1
    return x;
}

__device__ __forceinline__ unsigned bfr(float x) {          // f32 -> bf16 bits (RNE)
    unsigned u = __float_as_uint(x);
    return (u + 0x7FFFu + ((u >> 16) & 1u)) >> 16;
}

#define LD8V(dst, src)                                                    \
    {                                                                     \
        float4 t0_ = *(const float4*)(src);                               \
        float4 t1_ = *(const float4*)((src) + 4);                         \
        dst[0] = (v2f){t0_.x, t0_.y}; dst[1] = (v2f){t0_.z, t0_.w};       \
        dst[2] = (v2f){t1_.x, t1_.y}; dst[3] = (v2f){t1_.z, t1_.w};       \
    }

// ---- build bf16 ew LUT (nearest-neighbor), packed 2 channels per u32 word ----
__global__ void k_lut(const float* __restrict__ deW, const float* __restrict__ deb,
                      const float* __restrict__ deg, const float* __restrict__ debe,
                      unsigned* __restrict__ lutp) {
    int e = blockIdx.x * 4 + (threadIdx.x >> 6);
    int lane = threadIdx.x & 63;
    int c0 = 2 * lane, c1 = 2 * lane + 1;
    float d = e * (DMAX_ / (KLUT_ - 1));
    float s0 = expf(-d), s1 = expf(-0.5f * d), s2 = expf(-0.25f * d);
    float a0 = s0 * deW[c0] + s1 * deW[H_ + c0] + s2 * deW[2 * H_ + c0] + deb[c0];
    float a1 = s0 * deW[c1] + s1 * deW[H_ + c1] + s2 * deW[2 * H_ + c1] + deb[c1];
    float v0 = a0 / (1.f + expf(-a0));
    float v1 = a1 / (1.f + expf(-a1));
    float sum = v0 + v1, ssq = v0 * v0 + v1 * v1;
#pragma unroll
    for (int mask = 1; mask < 64; mask <<= 1) {
        sum += __shfl_xor(sum, mask);
        ssq += __shfl_xor(ssq, mask);
    }
    float mu = sum * (1.f / H_);
    float var = ssq * (1.f / H_) - mu * mu;
    float rstd = 1.f / sqrtf(var + EPS_);
    float r0 = (v0 - mu) * rstd * deg[c0] + debe[c0];
    float r1 = (v1 - mu) * rstd * deg[c1] + debe[c1];
    lutp[e * (H_ / 2) + lane] = bfr(r0) | (bfr(r1) << 16);
}

// ---------------- x = emb[an]; pre = x@Wi + msg_b; prj(bf16) = x@Wj ----------------
__global__ void k_embed_gemm(const int* __restrict__ an, const float* __restrict__ emb,
                             const float* __restrict__ W, const float* __restrict__ b,
                             float* __restrict__ x, float* __restrict__ preb,
                             ushort16* __restrict__ prj) {
    int i = blockIdx.x;
    int t = threadIdx.x;               // 256 threads
    __shared__ float xr[H_];
    if (t < H_) {
        float xv = emb[an[i] * H_ + t];
        xr[t] = xv;
        x[i * H_ + t] = xv;
    }
    __syncthreads();
    int h = t & (H_ - 1);
    int off = (t >= H_) ? H_ : 0;
    float s = 0.f;
#pragma unroll 4
    for (int k = 0; k < H_; k += 4) {
        float4 xv = *(const float4*)&xr[k];
        s = fmaf(xv.x, W[(off + k) * H_ + h], s);
        s = fmaf(xv.y, W[(off + k + 1) * H_ + h], s);
        s = fmaf(xv.z, W[(off + k + 2) * H_ + h], s);
        s = fmaf(xv.w, W[(off + k + 3) * H_ + h], s);
    }
    if (t >= H_) prj[i * H_ + h] = (ushort16)bfr(s);
    else         preb[i * H_ + h] = s + b[h];
}

// ---- jof stream: LDS-held LUT byte offset for tile t, pair-slot p (+cb2 prefolded) ----
__device__ __forceinline__ int ldjof(const int* jinfo, int t, int p, int cb2) {
    return jinfo[(t << 5) + p] + cb2;
}
__device__ __forceinline__ uint4 ldL(const unsigned* __restrict__ lutp, int jof) {
    return *(const uint4*)((const char*)lutp + jof);
}
__device__ __forceinline__ uint4 ldP(const char* __restrict__ prow) {
    return *(const uint4*)prow;
}

// ---- compute one j-tile from raw bf16x8 words: poly-silu + LN stats; accumulate ----
__device__ __forceinline__ void cmp_step(uint4 rl, uint4 rp,
                                         const v2f (&pbv)[4],
                                         v2f (&acc1)[4], v2f (&acc2)[4]) {
    unsigned lw[4] = {rl.x, rl.y, rl.z, rl.w};
    unsigned pw[4] = {rp.x, rp.y, rp.z, rp.w};
    v2f TM[4];
    v2f sum2 = {0.f, 0.f}, ssq2 = {0.f, 0.f};
#pragma unroll
    for (int k = 0; k < 4; ++k) {
        v2f tm = (v2f){__uint_as_float(pw[k] << 16),
                       __uint_as_float(pw[k] & 0xffff0000u)};
        v2f wv = pbv[k] + tm;
        v2f vc;
        vc.x = __builtin_amdgcn_fmed3f(wv.x, -4.0f, 4.0f);
        vc.y = __builtin_amdgcn_fmed3f(wv.y, -4.0f, 4.0f);
        v2f u = vc * vc;
        v2f pp = (v2f){PC3_, PC3_} * u + (v2f){PC2_, PC2_};
        pp = pp * u + (v2f){PC1_, PC1_};
        pp = pp * u + (v2f){PC0_, PC0_};
        v2f sg = vc * pp + (v2f){0.5f, 0.5f};   // sigmoid approx
        v2f vv = wv * sg;                        // silu
        TM[k] = vv;
        sum2 += vv;
        ssq2 += vv * vv;
    }
    float sum = rowreduce16(sum2.x + sum2.y);
    float ssq = rowreduce16(ssq2.x + ssq2.y);
    float mu = sum * (1.f / H_);
    float var = fmaf(ssq, 1.f / H_, -mu * mu);
    float rstd = __builtin_amdgcn_rsqf(var + EPS_);
    float c1 = -mu * rstd;
    v2f rstd2 = {rstd, rstd}, c12 = {c1, c1};
#pragma unroll
    for (int k = 0; k < 4; ++k) {
        v2f ew = (v2f){__uint_as_float(lw[k] << 16),
                       __uint_as_float(lw[k] & 0xffff0000u)};
        v2f t = TM[k] * rstd2 + c12;
        acc1[k] += t * ew;
        acc2[k] += ew;
    }
}

// ---------------- pairwise kernel + fused update + next-level pre/prj ----------------
// block = row i, 512 threads = 8 waves; each 16-lane row owns one pair (i,j);
// lane q owns 8 contiguous channels [8q, 8q+8).
// launch_bounds: (512,8) spills (r9: VGPR 32, FETCH 205MB, 3x slower); 6 is safe.
// j-loop: 4-slot rotation (A,B,C,D with per-slot jof regs — r14 parity lesson),
// TWO tiles computed per scheduling region so their independent dependency
// chains (silu poly + serial 16-lane DPP reduce) interleave on the VALU.
__global__ __launch_bounds__(512, 6) void k_pair(
    const float* __restrict__ pos, const float* __restrict__ x,
    const float* __restrict__ prebR, const ushort16* __restrict__ prjR,
    const unsigned* __restrict__ lutp,
    const float* __restrict__ mgp, const float* __restrict__ mbep,
    const float* __restrict__ uW, const float* __restrict__ ub,
    const float* __restrict__ ug, const float* __restrict__ ube,
    const float* __restrict__ Wn, const float* __restrict__ bn,
    float* __restrict__ xout, float* __restrict__ lmean,
    float* __restrict__ prebW, ushort16* __restrict__ prjW) {
    const int i = blockIdx.x;
    const int tid = threadIdx.x;
    const int w = tid >> 6;
    const int lane = tid & 63;
    const int g = lane >> 4;
    const int q = lane & 15;
    const int p = w * 4 + g;           // 0..31: pair slot
    const int cb = q * 8;              // channel base
    const int cb2 = cb * 2;            // byte offset of channel base (bf16)

    __shared__ int jinfo[N_ + 96];     // NN lut row byte offset per j (+pad: jof up to 33)
    __shared__ float red[32][H_];
    __shared__ float msums[H_], xrow[H_], xs[H_];
    __shared__ float part[4][H_];
    __shared__ float r4[2][2];

    v2f pbv[4], acc1[4], acc2[4];
    LD8V(pbv, prebR + i * H_ + cb);
#pragma unroll
    for (int k = 0; k < 4; ++k) { acc1[k] = (v2f){0.f, 0.f}; acc2[k] = (v2f){0.f, 0.f}; }

    const float pix = pos[3 * i], piy = pos[3 * i + 1], piz = pos[3 * i + 2];
    for (int j = tid; j < N_; j += 512) {
        float dx = pix - pos[3 * j];
        float dy = piy - pos[3 * j + 1];
        float dz = piz - pos[3 * j + 2];
        float sq = fmaf(dx, dx, fmaf(dy, dy, dz * dz));
        float d = __builtin_amdgcn_sqrtf(sq);
        float tf = fminf(d * TSCALE_, TMAX_);
        int i0 = (int)(tf + 0.5f);     // nearest entry
        jinfo[j] = i0 * ROWB_;
    }
    if (tid < 96) jinfo[N_ + tid] = 0; // pad: dead jof over-reads land here
    if (tid < H_) xrow[tid] = x[i * H_ + tid];
    __syncthreads();

    // ---- 4-slot pipeline, 2 tiles per compute region ----
    const char* prjRow = (const char*)prjR + p * ROWB_ + q * 16;   // tile t: +t*TILEB_
    int jA = ldjof(jinfo, 0, p, cb2);
    int jB = ldjof(jinfo, 1, p, cb2);
    int jC = ldjof(jinfo, 2, p, cb2);
    int jD = ldjof(jinfo, 3, p, cb2);
    uint4 LA = ldL(lutp, jA), PA = ldP(prjRow);
    jA = ldjof(jinfo, 4, p, cb2);
    uint4 LB = ldL(lutp, jB), PB = ldP(prjRow + 1 * TILEB_);
    jB = ldjof(jinfo, 5, p, cb2);
    __builtin_amdgcn_sched_barrier(0);
    uint4 LC, PC, LD_, PD;
    for (int t = 0; t <= NT_ - 8; t += 4) {            // t = 0,4,...,24
        LC = ldL(lutp, jC); PC = ldP(prjRow + (t + 2) * TILEB_);
        jC = ldjof(jinfo, t + 6, p, cb2);
        LD_ = ldL(lutp, jD); PD = ldP(prjRow + (t + 3) * TILEB_);
        jD = ldjof(jinfo, t + 7, p, cb2);
        __builtin_amdgcn_sched_barrier(0);
        cmp_step(LA, PA, pbv, acc1, acc2);             // tile t
        cmp_step(LB, PB, pbv, acc1, acc2);             // tile t+1 (same region)
        __builtin_amdgcn_sched_barrier(0);
        LA = ldL(lutp, jA); PA = ldP(prjRow + (t + 4) * TILEB_);
        jA = ldjof(jinfo, t + 8, p, cb2);              // t=24 -> jof(32): pad (dead)
        LB = ldL(lutp, jB); PB = ldP(prjRow + (t + 5) * TILEB_);
        jB = ldjof(jinfo, t + 9, p, cb2);              // t=24 -> jof(33): pad (dead)
        __builtin_amdgcn_sched_barrier(0);
        cmp_step(LC, PC, pbv, acc1, acc2);             // tile t+2
        cmp_step(LD_, PD, pbv, acc1, acc2);            // tile t+3 (same region)
        __builtin_amdgcn_sched_barrier(0);
    }
    // after t=24 iter: A,B hold tiles 28,29; jC=jof(30), jD=jof(31)
    LC = ldL(lutp, jC); PC = ldP(prjRow + 30 * TILEB_);
    LD_ = ldL(lutp, jD); PD = ldP(prjRow + 31 * TILEB_);
    __builtin_amdgcn_sched_barrier(0);
    cmp_step(LA, PA, pbv, acc1, acc2);                 // tile 28
    cmp_step(LB, PB, pbv, acc1, acc2);                 // tile 29
    __builtin_amdgcn_sched_barrier(0);
    cmp_step(LC, PC, pbv, acc1, acc2);                 // tile 30
    cmp_step(LD_, PD, pbv, acc1, acc2);                // tile 31

    // ---- apply g/be and combine 32 pair-slot partials -> msum (block-local) ----
    v2f mgv[4], mbev[4], accv[4];
    LD8V(mgv, mgp + cb);
    LD8V(mbev, mbep + cb);
#pragma unroll
    for (int k = 0; k < 4; ++k)
        accv[k] = mgv[k] * acc1[k] + mbev[k] * acc2[k];
    *(float4*)&red[p][cb] = make_float4(accv[0].x, accv[0].y, accv[1].x, accv[1].y);
    *(float4*)&red[p][cb + 4] = make_float4(accv[2].x, accv[2].y, accv[3].x, accv[3].y);
    __syncthreads();
    if (tid < H_) {
        float s = 0.f;
#pragma unroll
        for (int pp = 0; pp < 32; ++pp) s += red[pp][tid];
        msums[tid] = s;
    }
    __syncthreads();

    // ---- fused update: x += LN(silu([x,msum]@uW+ub)); lmean += x ----
    int h = tid & (H_ - 1);
    int seg = tid >> 7;                // 4-way K split
    const float* src = (seg == 0) ? xrow : (seg == 1) ? xrow + 64
                     : (seg == 2) ? msums : msums + 64;
    const float* Wp = uW + (seg * 64) * H_ + h;
    float s2 = 0.f;
#pragma unroll 4
    for (int k = 0; k < 64; k += 4) {
        float4 uv = *(const float4*)&src[k];
        s2 = fmaf(uv.x, Wp[(k + 0) * H_], s2);
        s2 = fmaf(uv.y, Wp[(k + 1) * H_], s2);
        s2 = fmaf(uv.z, Wp[(k + 2) * H_], s2);
        s2 = fmaf(uv.w, Wp[(k + 3) * H_], s2);
    }
    part[seg][h] = s2;
    __syncthreads();
    float v = 0.f;
    if (tid < H_) {
        float sv = part[0][tid] + part[1][tid] + part[2][tid] + part[3][tid] + ub[tid];
        v = sv * fsig(sv);
    }
    float sum = v, ssq = v * v;
#pragma unroll
    for (int mask = 1; mask < 64; mask <<= 1) {
        sum += __shfl_xor(sum, mask);
        ssq += __shfl_xor(ssq, mask);
    }
    if (tid < H_ && (tid & 63) == 0) { r4[tid >> 6][0] = sum; r4[tid >> 6][1] = ssq; }
    __syncthreads();
    if (tid < H_) {
        sum = r4[0][0] + r4[1][0];
        ssq = r4[0][1] + r4[1][1];
        float mu = sum * (1.f / H_);
        float var = fmaf(ssq, 1.f / H_, -mu * mu);
        float rstd = rsqrtf(var + EPS_);
        float xn = xrow[tid] + fmaf((v - mu) * rstd, ug[tid], ube[tid]);
        xs[tid] = xn;
        xout[i * H_ + tid] = xn;
        atomicAdd(&lmean[tid], xn);
    }

    // ---- fused next-level pre/prj = xs @ Wn (+bn), into ping-pong buffers ----
    if (Wn) {
        __syncthreads();               // xs ready; also all part reads done
        int which = tid >> 8;          // 0 = pre, 1 = prj
        int kh = (tid >> 7) & 1;       // K half
        const float* Wp2 = Wn + (which * H_ + kh * 64) * H_ + h;
        const float* xsrc = xs + kh * 64;
        float s3 = 0.f;
#pragma unroll 4
        for (int k = 0; k < 64; k += 4) {
            float4 xv = *(const float4*)&xsrc[k];
            s3 = fmaf(xv.x, Wp2[(k + 0) * H_], s3);
            s3 = fmaf(xv.y, Wp2[(k + 1) * H_], s3);
            s3 = fmaf(xv.z, Wp2[(k + 2) * H_], s3);
            s3 = fmaf(xv.w, Wp2[(k + 3) * H_], s3);
        }
        part[(which << 1) | kh][h] = s3;
        __syncthreads();
        if (tid < 256) {
            int wh = tid >> 7, h3 = tid & 127;
            float val = part[wh * 2][h3] + part[wh * 2 + 1][h3];
            if (wh) prjW[i * H_ + h3] = (ushort16)bfr(val);
            else    prebW[i * H_ + h3] = val + bn[h3];
        }
    }
}

// ---------------- out = LN(combined @ fp_W + fp_b) ----------------
__global__ void k_final(const float* __restrict__ lmean, const float* __restrict__ fpW,
                        const float* __restrict__ fpb, const float* __restrict__ fpg,
                        const float* __restrict__ fpbe, float* __restrict__ out) {
    int t = threadIdx.x;               // 256 threads
    __shared__ float comb[L_ * H_];
    comb[t] = lmean[t] * (1.f / N_);
    if (t < L_ * H_ - D_) comb[D_ + t] = lmean[D_ + t] * (1.f / N_);
    __syncthreads();
    float s = fpb[t];
#pragma unroll 8
    for (int k = 0; k < L_ * H_; ++k)
        s = fmaf(comb[k], fpW[k * D_ + t], s);
    float sum = s, ssq = s * s;
#pragma unroll
    for (int mask = 1; mask < 64; mask <<= 1) {
        sum += __shfl_xor(sum, mask);
        ssq += __shfl_xor(ssq, mask);
    }
    __shared__ float r4[4][2];
    int wv = t >> 6;
    if ((t & 63) == 0) { r4[wv][0] = sum; r4[wv][1] = ssq; }
    __syncthreads();
    sum = r4[0][0] + r4[1][0] + r4[2][0] + r4[3][0];
    ssq = r4[0][1] + r4[1][1] + r4[2][1] + r4[3][1];
    float mu = sum * (1.f / D_);
    float var = fmaf(ssq, 1.f / D_, -mu * mu);
    float rstd = rsqrtf(var + EPS_);
    out[t] = fmaf((s - mu) * rstd, fpg[t], fpbe[t]);
}

extern "C" void kernel_launch(void* const* d_in, const int* in_sizes, int n_in,
                              void* d_out, int out_size, void* d_ws, size_t ws_size,
                              hipStream_t stream) {
    const int*   an    = (const int*)d_in[0];
    const float* pos   = (const float*)d_in[1];
    const float* emb   = (const float*)d_in[2];
    const float* deW   = (const float*)d_in[3];
    const float* deb   = (const float*)d_in[4];
    const float* deg   = (const float*)d_in[5];
    const float* debe  = (const float*)d_in[6];
    const float* msgW  = (const float*)d_in[7];
    const float* msgb  = (const float*)d_in[8];
    const float* msgg  = (const float*)d_in[9];
    const float* msgbe = (const float*)d_in[10];
    const float* updW  = (const float*)d_in[11];
    const float* updb  = (const float*)d_in[12];
    const float* updg  = (const float*)d_in[13];
    const float* updbe = (const float*)d_in[14];
    const float* fpW   = (const float*)d_in[15];
    const float* fpb   = (const float*)d_in[16];
    const float* fpg   = (const float*)d_in[17];
    const float* fpbe  = (const float*)d_in[18];
    float* out = (float*)d_out;

    float* ws    = (float*)d_ws;
    float* x     = ws;                               // N*H f32
    float* prebA = x + N_ * H_;                      // N*H f32
    float* prebB = prebA + N_ * H_;                  // N*H f32
    ushort16* prjA = (ushort16*)(prebB + N_ * H_);   // N*H bf16
    ushort16* prjB = prjA + N_ * H_;                 // N*H bf16
    float* lmean = (float*)(prjB + N_ * H_);         // L*H f32
    unsigned* lutp = (unsigned*)(lmean + L_ * H_);   // KLUT * H/2 words (2 MB)

    hipMemsetAsync(lmean, 0, L_ * H_ * sizeof(float), stream);
    k_lut<<<KLUT_ / 4, 256, 0, stream>>>(deW, deb, deg, debe, lutp);
    k_embed_gemm<<<N_, 256, 0, stream>>>(an, emb, msgW, msgb, x, prebA, prjA);
    for (int lvl = 0; lvl < L_; ++lvl) {
        const float* pR  = (lvl & 1) ? prebB : prebA;
        const ushort16* prR = (lvl & 1) ? prjB : prjA;
        float* pW  = (lvl & 1) ? prebA : prebB;
        ushort16* prW = (lvl & 1) ? prjA : prjB;
        const float* Wn = (lvl < L_ - 1) ? msgW + (lvl + 1) * 2 * H_ * H_ : nullptr;
        const float* bn = (lvl < L_ - 1) ? msgb + (lvl + 1) * H_ : nullptr;
        k_pair<<<N_, 512, 0, stream>>>(pos, x, pR, prR, lutp,
                                       msgg + lvl * H_, msgbe + lvl * H_,
                                       updW + lvl * 2 * H_ * H_, updb + lvl * H_,
                                       updg + lvl * H_, updbe + lvl * H_,
                                       Wn, bn, x, lmean + lvl * H_, pW, prW);
    }
    k_final<<<1, D_, 0, stream>>>(lmean, fpW, fpb, fpg, fpbe, out);
}

// Round 17
// 199.562 us; speedup vs baseline: 1.5426x; 1.5426x over previous
//
#include <hip/hip_runtime.h>
#include <math.h>

constexpr int N_ = 1024;
constexpr int H_ = 128;
constexpr int D_ = 256;
constexpr int L_ = 3;
constexpr int NT_ = N_ / 32;           // j-tiles per block
constexpr int ROWB_ = H_ * 2;          // bytes per bf16 row (lut / prj)
constexpr int TILEB_ = 32 * ROWB_;     // bytes per j-tile of prj
constexpr float EPS_ = 1e-5f;
constexpr float LOG2E_ = 1.44269504f;
constexpr int KLUT_ = 8192;
constexpr float DMAX_ = 40.0f;
constexpr float TSCALE_ = (KLUT_ - 1) / DMAX_;
constexpr float TMAX_ = (float)(KLUT_ - 1) - 0.001f;

// odd deg-7 fit of (sigmoid(x)-0.5)/x in u=x^2 over [0,16] (Chebyshev nodes);
// |sigmoid err| <~ 2e-3 on [-4,4]
constexpr float PC0_ = 0.2487467f;
constexpr float PC1_ = -0.0181606f;
constexpr float PC2_ = 0.0010210f;
constexpr float PC3_ = -2.4300e-5f;

typedef float v2f __attribute__((ext_vector_type(2)));
typedef unsigned u32x4 __attribute__((ext_vector_type(4)));
typedef unsigned short ushort16;

__device__ __forceinline__ float fsig(float v) {            // sigmoid (trans path)
    float e = __builtin_amdgcn_exp2f(v * -LOG2E_);
    return __builtin_amdgcn_rcpf(1.0f + e);
}

template <int CTRL>
__device__ __forceinline__ float rowadd(float x) {
    int y = __builtin_amdgcn_update_dpp(0, __float_as_int(x), CTRL, 0xF, 0xF, true);
    return x + __int_as_float(y);
}
__device__ __forceinline__ float rowreduce16(float x) {
    x = rowadd<0x128>(x);   // row_ror:8
    x = rowadd<0x124>(x);   // row_ror:4
    x = rowadd<0x122>(x);   // row_ror:2
    x = rowadd<0x121>(x);   // row_ror:1
    return x;
}

__device__ __forceinline__ unsigned bfr(float x) {          // f32 -> bf16 bits (RNE)
    unsigned u = __float_as_uint(x);
    return (u + 0x7FFFu + ((u >> 16) & 1u)) >> 16;
}

#define LD8V(dst, src)                                                    \
    {                                                                     \
        float4 t0_ = *(const float4*)(src);                               \
        float4 t1_ = *(const float4*)((src) + 4);                         \
        dst[0] = (v2f){t0_.x, t0_.y}; dst[1] = (v2f){t0_.z, t0_.w};       \
        dst[2] = (v2f){t1_.x, t1_.y}; dst[3] = (v2f){t1_.z, t1_.w};       \
    }

// ---- compiler-opaque 16B load: cannot be sunk/flattened/spilled-around ----
__device__ __forceinline__ void asm_ld(u32x4& dst, const void* addr) {
    asm volatile("global_load_dwordx4 %0, %1, off" : "=&v"(dst) : "v"(addr));
}
// counted vmcnt wait + scheduling fence (rule #18)
#define VWAIT(N)                                                          \
    do {                                                                  \
        asm volatile("s_waitcnt vmcnt(" #N ")");                          \
        __builtin_amdgcn_sched_barrier(0);                                \
    } while (0)

// ---- build bf16 ew LUT (nearest-neighbor), packed 2 channels per u32 word ----
__global__ void k_lut(const float* __restrict__ deW, const float* __restrict__ deb,
                      const float* __restrict__ deg, const float* __restrict__ debe,
                      unsigned* __restrict__ lutp) {
    int e = blockIdx.x * 4 + (threadIdx.x >> 6);
    int lane = threadIdx.x & 63;
    int c0 = 2 * lane, c1 = 2 * lane + 1;
    float d = e * (DMAX_ / (KLUT_ - 1));
    float s0 = expf(-d), s1 = expf(-0.5f * d), s2 = expf(-0.25f * d);
    float a0 = s0 * deW[c0] + s1 * deW[H_ + c0] + s2 * deW[2 * H_ + c0] + deb[c0];
    float a1 = s0 * deW[c1] + s1 * deW[H_ + c1] + s2 * deW[2 * H_ + c1] + deb[c1];
    float v0 = a0 / (1.f + expf(-a0));
    float v1 = a1 / (1.f + expf(-a1));
    float sum = v0 + v1, ssq = v0 * v0 + v1 * v1;
#pragma unroll
    for (int mask = 1; mask < 64; mask <<= 1) {
        sum += __shfl_xor(sum, mask);
        ssq += __shfl_xor(ssq, mask);
    }
    float mu = sum * (1.f / H_);
    float var = ssq * (1.f / H_) - mu * mu;
    float rstd = 1.f / sqrtf(var + EPS_);
    float r0 = (v0 - mu) * rstd * deg[c0] + debe[c0];
    float r1 = (v1 - mu) * rstd * deg[c1] + debe[c1];
    lutp[e * (H_ / 2) + lane] = bfr(r0) | (bfr(r1) << 16);
}

// ---------------- x = emb[an]; pre = x@Wi + msg_b; prj(bf16) = x@Wj ----------------
__global__ void k_embed_gemm(const int* __restrict__ an, const float* __restrict__ emb,
                             const float* __restrict__ W, const float* __restrict__ b,
                             float* __restrict__ x, float* __restrict__ preb,
                             ushort16* __restrict__ prj) {
    int i = blockIdx.x;
    int t = threadIdx.x;               // 256 threads
    __shared__ float xr[H_];
    if (t < H_) {
        float xv = emb[an[i] * H_ + t];
        xr[t] = xv;
        x[i * H_ + t] = xv;
    }
    __syncthreads();
    int h = t & (H_ - 1);
    int off = (t >= H_) ? H_ : 0;
    float s = 0.f;
#pragma unroll 4
    for (int k = 0; k < H_; k += 4) {
        float4 xv = *(const float4*)&xr[k];
        s = fmaf(xv.x, W[(off + k) * H_ + h], s);
        s = fmaf(xv.y, W[(off + k + 1) * H_ + h], s);
        s = fmaf(xv.z, W[(off + k + 2) * H_ + h], s);
        s = fmaf(xv.w, W[(off + k + 3) * H_ + h], s);
    }
    if (t >= H_) prj[i * H_ + h] = (ushort16)bfr(s);
    else         preb[i * H_ + h] = s + b[h];
}

// ---- jof stream: LDS-held LUT byte offset for tile t, pair-slot p (+cb2 prefolded) ----
__device__ __forceinline__ int ldjof(const int* jinfo, int t, int p, int cb2) {
    return jinfo[(t << 5) + p] + cb2;
}

// ---- compute one j-tile from raw bf16x8 words: poly-silu + LN stats; accumulate ----
__device__ __forceinline__ void cmp_step(u32x4 rl, u32x4 rp,
                                         const v2f (&pbv)[4],
                                         v2f (&acc1)[4], v2f (&acc2)[4]) {
    v2f TM[4];
    v2f sum2 = {0.f, 0.f}, ssq2 = {0.f, 0.f};
#pragma unroll
    for (int k = 0; k < 4; ++k) {
        unsigned pw = rp[k];
        v2f tm = (v2f){__uint_as_float(pw << 16),
                       __uint_as_float(pw & 0xffff0000u)};
        v2f wv = pbv[k] + tm;
        v2f vc;
        vc.x = __builtin_amdgcn_fmed3f(wv.x, -4.0f, 4.0f);
        vc.y = __builtin_amdgcn_fmed3f(wv.y, -4.0f, 4.0f);
        v2f u = vc * vc;
        v2f pp = (v2f){PC3_, PC3_} * u + (v2f){PC2_, PC2_};
        pp = pp * u + (v2f){PC1_, PC1_};
        pp = pp * u + (v2f){PC0_, PC0_};
        v2f sg = vc * pp + (v2f){0.5f, 0.5f};   // sigmoid approx
        v2f vv = wv * sg;                        // silu
        TM[k] = vv;
        sum2 += vv;
        ssq2 += vv * vv;
    }
    float sum = rowreduce16(sum2.x + sum2.y);
    float ssq = rowreduce16(ssq2.x + ssq2.y);
    float mu = sum * (1.f / H_);
    float var = fmaf(ssq, 1.f / H_, -mu * mu);
    float rstd = __builtin_amdgcn_rsqf(var + EPS_);
    float c1 = -mu * rstd;
    v2f rstd2 = {rstd, rstd}, c12 = {c1, c1};
#pragma unroll
    for (int k = 0; k < 4; ++k) {
        unsigned lw = rl[k];
        v2f ew = (v2f){__uint_as_float(lw << 16),
                       __uint_as_float(lw & 0xffff0000u)};
        v2f t = TM[k] * rstd2 + c12;
        acc1[k] += t * ew;
        acc2[k] += ew;
    }
}

// ---------------- pairwise kernel + fused update + next-level pre/prj ----------------
// block = row i, 512 threads = 8 waves; each 16-lane row owns one pair (i,j);
// lane q owns 8 contiguous channels [8q, 8q+8).
// launch_bounds: (512,8) spills (r9); 6 is the safe point.
// j-loop: 3-slot rotation with INLINE-ASM loads + counted vmcnt(4) (T4 pattern) —
// the compiler cannot flatten (r8/r13/r15, VGPR 40) or spill (r16, WRITE 96MB)
// asm-volatile loads. Steady state: 6 loads outstanding, vmcnt(4) retires
// exactly the consumed tile; load-to-use = 2 compute regions (~400cy > L2 lat).
__global__ __launch_bounds__(512, 6) void k_pair(
    const float* __restrict__ pos, const float* __restrict__ x,
    const float* __restrict__ prebR, const ushort16* __restrict__ prjR,
    const unsigned* __restrict__ lutp,
    const float* __restrict__ mgp, const float* __restrict__ mbep,
    const float* __restrict__ uW, const float* __restrict__ ub,
    const float* __restrict__ ug, const float* __restrict__ ube,
    const float* __restrict__ Wn, const float* __restrict__ bn,
    float* __restrict__ xout, float* __restrict__ lmean,
    float* __restrict__ prebW, ushort16* __restrict__ prjW) {
    const int i = blockIdx.x;
    const int tid = threadIdx.x;
    const int w = tid >> 6;
    const int lane = tid & 63;
    const int g = lane >> 4;
    const int q = lane & 15;
    const int p = w * 4 + g;           // 0..31: pair slot
    const int cb = q * 8;              // channel base
    const int cb2 = cb * 2;            // byte offset of channel base (bf16)

    __shared__ int jinfo[N_ + 96];     // NN lut row byte offset per j (+pad to jof(34))
    __shared__ float red[32][H_];
    __shared__ float msums[H_], xrow[H_], xs[H_];
    __shared__ float part[4][H_];
    __shared__ float r4[2][2];

    v2f pbv[4], acc1[4], acc2[4];
    LD8V(pbv, prebR + i * H_ + cb);
#pragma unroll
    for (int k = 0; k < 4; ++k) { acc1[k] = (v2f){0.f, 0.f}; acc2[k] = (v2f){0.f, 0.f}; }

    const float pix = pos[3 * i], piy = pos[3 * i + 1], piz = pos[3 * i + 2];
    for (int j = tid; j < N_; j += 512) {
        float dx = pix - pos[3 * j];
        float dy = piy - pos[3 * j + 1];
        float dz = piz - pos[3 * j + 2];
        float sq = fmaf(dx, dx, fmaf(dy, dy, dz * dz));
        float d = __builtin_amdgcn_sqrtf(sq);
        float tf = fminf(d * TSCALE_, TMAX_);
        int i0 = (int)(tf + 0.5f);     // nearest entry
        jinfo[j] = i0 * ROWB_;
    }
    if (tid < 96) jinfo[N_ + tid] = 0; // pad: dead jof over-reads land here
    if (tid < H_) xrow[tid] = x[i * H_ + tid];
    __syncthreads();
    // drain ALL tracked memory ops so SIInsertWaitcnts places no waits in the loop
    __builtin_amdgcn_s_waitcnt(0);

    // ---- 3-slot asm pipeline with counted vmcnt ----
    const char* prjRow = (const char*)prjR + p * ROWB_ + q * 16;   // tile t: +t*TILEB_
    const char* lutb = (const char*)lutp;
    int j0 = ldjof(jinfo, 0, p, cb2);
    int j1 = ldjof(jinfo, 1, p, cb2);
    int j2 = ldjof(jinfo, 2, p, cb2);
    u32x4 L0, P0, L1, P1, L2, P2;
    asm_ld(L0, lutb + j0); asm_ld(P0, prjRow);
    j0 = ldjof(jinfo, 3, p, cb2);
    asm_ld(L1, lutb + j1); asm_ld(P1, prjRow + 1 * TILEB_);
    j1 = ldjof(jinfo, 4, p, cb2);
    __builtin_amdgcn_sched_barrier(0);
    for (int t = 0; t < NT_ - 2; t += 3) {             // t = 0,3,...,27
        asm_ld(L2, lutb + j2); asm_ld(P2, prjRow + (t + 2) * TILEB_);
        j2 = ldjof(jinfo, t + 5, p, cb2);
        VWAIT(4);
        cmp_step(L0, P0, pbv, acc1, acc2);             // tile t
        __builtin_amdgcn_sched_barrier(0);
        asm_ld(L0, lutb + j0); asm_ld(P0, prjRow + (t + 3) * TILEB_);
        j0 = ldjof(jinfo, t + 6, p, cb2);
        VWAIT(4);
        cmp_step(L1, P1, pbv, acc1, acc2);             // tile t+1
        __builtin_amdgcn_sched_barrier(0);
        asm_ld(L1, lutb + j1); asm_ld(P1, prjRow + (t + 4) * TILEB_);
        j1 = ldjof(jinfo, t + 7, p, cb2);              // t=27 -> jof(34): pad (dead)
        VWAIT(4);
        cmp_step(L2, P2, pbv, acc1, acc2);             // tile t+2
        __builtin_amdgcn_sched_barrier(0);
    }
    // after loop: L0/P0 = tile 30 in flight, L1/P1 = tile 31 in flight
    VWAIT(2);
    cmp_step(L0, P0, pbv, acc1, acc2);                 // tile 30
    VWAIT(0);
    cmp_step(L1, P1, pbv, acc1, acc2);                 // tile 31

    // ---- apply g/be and combine 32 pair-slot partials -> msum (block-local) ----
    v2f mgv[4], mbev[4], accv[4];
    LD8V(mgv, mgp + cb);
    LD8V(mbev, mbep + cb);
#pragma unroll
    for (int k = 0; k < 4; ++k)
        accv[k] = mgv[k] * acc1[k] + mbev[k] * acc2[k];
    *(float4*)&red[p][cb] = make_float4(accv[0].x, accv[0].y, accv[1].x, accv[1].y);
    *(float4*)&red[p][cb + 4] = make_float4(accv[2].x, accv[2].y, accv[3].x, accv[3].y);
    __syncthreads();
    if (tid < H_) {
        float s = 0.f;
#pragma unroll
        for (int pp = 0; pp < 32; ++pp) s += red[pp][tid];
        msums[tid] = s;
    }
    __syncthreads();

    // ---- fused update: x += LN(silu([x,msum]@uW+ub)); lmean += x ----
    int h = tid & (H_ - 1);
    int seg = tid >> 7;                // 4-way K split
    const float* src = (seg == 0) ? xrow : (seg == 1) ? xrow + 64
                     : (seg == 2) ? msums : msums + 64;
    const float* Wp = uW + (seg * 64) * H_ + h;
    float s2 = 0.f;
#pragma unroll 4
    for (int k = 0; k < 64; k += 4) {
        float4 uv = *(const float4*)&src[k];
        s2 = fmaf(uv.x, Wp[(k + 0) * H_], s2);
        s2 = fmaf(uv.y, Wp[(k + 1) * H_], s2);
        s2 = fmaf(uv.z, Wp[(k + 2) * H_], s2);
        s2 = fmaf(uv.w, Wp[(k + 3) * H_], s2);
    }
    part[seg][h] = s2;
    __syncthreads();
    float v = 0.f;
    if (tid < H_) {
        float sv = part[0][tid] + part[1][tid] + part[2][tid] + part[3][tid] + ub[tid];
        v = sv * fsig(sv);
    }
    float sum = v, ssq = v * v;
#pragma unroll
    for (int mask = 1; mask < 64; mask <<= 1) {
        sum += __shfl_xor(sum, mask);
        ssq += __shfl_xor(ssq, mask);
    }
    if (tid < H_ && (tid & 63) == 0) { r4[tid >> 6][0] = sum; r4[tid >> 6][1] = ssq; }
    __syncthreads();
    if (tid < H_) {
        sum = r4[0][0] + r4[1][0];
        ssq = r4[0][1] + r4[1][1];
        float mu = sum * (1.f / H_);
        float var = fmaf(ssq, 1.f / H_, -mu * mu);
        float rstd = rsqrtf(var + EPS_);
        float xn = xrow[tid] + fmaf((v - mu) * rstd, ug[tid], ube[tid]);
        xs[tid] = xn;
        xout[i * H_ + tid] = xn;
        atomicAdd(&lmean[tid], xn);
    }

    // ---- fused next-level pre/prj = xs @ Wn (+bn), into ping-pong buffers ----
    if (Wn) {
        __syncthreads();               // xs ready; also all part reads done
        int which = tid >> 8;          // 0 = pre, 1 = prj
        int kh = (tid >> 7) & 1;       // K half
        const float* Wp2 = Wn + (which * H_ + kh * 64) * H_ + h;
        const float* xsrc = xs + kh * 64;
        float s3 = 0.f;
#pragma unroll 4
        for (int k = 0; k < 64; k += 4) {
            float4 xv = *(const float4*)&xsrc[k];
            s3 = fmaf(xv.x, Wp2[(k + 0) * H_], s3);
            s3 = fmaf(xv.y, Wp2[(k + 1) * H_], s3);
            s3 = fmaf(xv.z, Wp2[(k + 2) * H_], s3);
            s3 = fmaf(xv.w, Wp2[(k + 3) * H_], s3);
        }
        part[(which << 1) | kh][h] = s3;
        __syncthreads();
        if (tid < 256) {
            int wh = tid >> 7, h3 = tid & 127;
            float val = part[wh * 2][h3] + part[wh * 2 + 1][h3];
            if (wh) prjW[i * H_ + h3] = (ushort16)bfr(val);
            else    prebW[i * H_ + h3] = val + bn[h3];
        }
    }
}

// ---------------- out = LN(combined @ fp_W + fp_b) ----------------
__global__ void k_final(const float* __restrict__ lmean, const float* __restrict__ fpW,
                        const float* __restrict__ fpb, const float* __restrict__ fpg,
                        const float* __restrict__ fpbe, float* __restrict__ out) {
    int t = threadIdx.x;               // 256 threads
    __shared__ float comb[L_ * H_];
    comb[t] = lmean[t] * (1.f / N_);
    if (t < L_ * H_ - D_) comb[D_ + t] = lmean[D_ + t] * (1.f / N_);
    __syncthreads();
    float s = fpb[t];
#pragma unroll 8
    for (int k = 0; k < L_ * H_; ++k)
        s = fmaf(comb[k], fpW[k * D_ + t], s);
    float sum = s, ssq = s * s;
#pragma unroll
    for (int mask = 1; mask < 64; mask <<= 1) {
        sum += __shfl_xor(sum, mask);
        ssq += __shfl_xor(ssq, mask);
    }
    __shared__ float r4[4][2];
    int wv = t >> 6;
    if ((t & 63) == 0) { r4[wv][0] = sum; r4[wv][1] = ssq; }
    __syncthreads();
    sum = r4[0][0] + r4[1][0] + r4[2][0] + r4[3][0];
    ssq = r4[0][1] + r4[1][1] + r4[2][1] + r4[3][1];
    float mu = sum * (1.f / D_);
    float var = fmaf(ssq, 1.f / D_, -mu * mu);
    float rstd = rsqrtf(var + EPS_);
    out[t] = fmaf((s - mu) * rstd, fpg[t], fpbe[t]);
}

extern "C" void kernel_launch(void* const* d_in, const int* in_sizes, int n_in,
                              void* d_out, int out_size, void* d_ws, size_t ws_size,
                              hipStream_t stream) {
    const int*   an    = (const int*)d_in[0];
    const float* pos   = (const float*)d_in[1];
    const float* emb   = (const float*)d_in[2];
    const float* deW   = (const float*)d_in[3];
    const float* deb   = (const float*)d_in[4];
    const float* deg   = (const float*)d_in[5];
    const float* debe  = (const float*)d_in[6];
    const float* msgW  = (const float*)d_in[7];
    const float* msgb  = (const float*)d_in[8];
    const float* msgg  = (const float*)d_in[9];
    const float* msgbe = (const float*)d_in[10];
    const float* updW  = (const float*)d_in[11];
    const float* updb  = (const float*)d_in[12];
    const float* updg  = (const float*)d_in[13];
    const float* updbe = (const float*)d_in[14];
    const float* fpW   = (const float*)d_in[15];
    const float* fpb   = (const float*)d_in[16];
    const float* fpg   = (const float*)d_in[17];
    const float* fpbe  = (const float*)d_in[18];
    float* out = (float*)d_out;

    float* ws    = (float*)d_ws;
    float* x     = ws;                               // N*H f32
    float* prebA = x + N_ * H_;                      // N*H f32
    float* prebB = prebA + N_ * H_;                  // N*H f32
    ushort16* prjA = (ushort16*)(prebB + N_ * H_);   // N*H bf16
    ushort16* prjB = prjA + N_ * H_;                 // N*H bf16
    float* lmean = (float*)(prjB + N_ * H_);         // L*H f32
    unsigned* lutp = (unsigned*)(lmean + L_ * H_);   // KLUT * H/2 words (2 MB)

    hipMemsetAsync(lmean, 0, L_ * H_ * sizeof(float), stream);
    k_lut<<<KLUT_ / 4, 256, 0, stream>>>(deW, deb, deg, debe, lutp);
    k_embed_gemm<<<N_, 256, 0, stream>>>(an, emb, msgW, msgb, x, prebA, prjA);
    for (int lvl = 0; lvl < L_; ++lvl) {
        const float* pR  = (lvl & 1) ? prebB : prebA;
        const ushort16* prR = (lvl & 1) ? prjB : prjA;
        float* pW  = (lvl & 1) ? prebA : prebB;
        ushort16* prW = (lvl & 1) ? prjA : prjB;
        const float* Wn = (lvl < L_ - 1) ? msgW + (lvl + 1) * 2 * H_ * H_ : nullptr;
        const float* bn = (lvl < L_ - 1) ? msgb + (lvl + 1) * H_ : nullptr;
        k_pair<<<N_, 512, 0, stream>>>(pos, x, pR, prR, lutp,
                                       msgg + lvl * H_, msgbe + lvl * H_,
                                       updW + lvl * 2 * H_ * H_, updb + lvl * H_,
                                       updg + lvl * H_, updbe + lvl * H_,
                                       Wn, bn, x, lmean + lvl * H_, pW, prW);
    }
    k_final<<<1, D_, 0, stream>>>(lmean, fpW, fpb, fpg, fpbe, out);
}

// Round 19
// 198.928 us; speedup vs baseline: 1.5475x; 1.0032x over previous
//
#include <hip/hip_runtime.h>
#include <math.h>

constexpr int N_ = 1024;
constexpr int H_ = 128;
constexpr int D_ = 256;
constexpr int L_ = 3;
constexpr int NT_ = N_ / 32;           // j-tiles per block
constexpr int ROWB_ = H_ * 2;          // bytes per bf16 row (lut / prj)
constexpr int TILEB_ = 32 * ROWB_;     // bytes per j-tile of prj
constexpr float EPS_ = 1e-5f;
constexpr float LOG2E_ = 1.44269504f;
constexpr int KLUT_ = 8192;
constexpr float DMAX_ = 40.0f;
constexpr float TSCALE_ = (KLUT_ - 1) / DMAX_;
constexpr float TMAX_ = (float)(KLUT_ - 1) - 0.001f;

// odd deg-7 fit of (sigmoid(x)-0.5)/x in u=x^2 over [0,16] (Chebyshev nodes);
// |sigmoid err| <~ 2e-3 on [-4,4]
constexpr float PC0_ = 0.2487467f;
constexpr float PC1_ = -0.0181606f;
constexpr float PC2_ = 0.0010210f;
constexpr float PC3_ = -2.4300e-5f;

typedef float v2f __attribute__((ext_vector_type(2)));
typedef unsigned u32x4 __attribute__((ext_vector_type(4)));
typedef unsigned short ushort16;

__device__ __forceinline__ v2f fma2(v2f a, v2f b, v2f c) {
    return __builtin_elementwise_fma(a, b, c);
}

__device__ __forceinline__ float fsig(float v) {            // sigmoid (trans path)
    float e = __builtin_amdgcn_exp2f(v * -LOG2E_);
    return __builtin_amdgcn_rcpf(1.0f + e);
}

template <int CTRL>
__device__ __forceinline__ float rowadd(float x) {
    int y = __builtin_amdgcn_update_dpp(0, __float_as_int(x), CTRL, 0xF, 0xF, true);
    return x + __int_as_float(y);
}
__device__ __forceinline__ float rowreduce16(float x) {
    x = rowadd<0x128>(x);   // row_ror:8
    x = rowadd<0x124>(x);   // row_ror:4
    x = rowadd<0x122>(x);   // row_ror:2
    x = rowadd<0x121>(x);   // row_ror:1
    return x;
}

__device__ __forceinline__ unsigned bfr(float x) {          // f32 -> bf16 bits (RNE)
    unsigned u = __float_as_uint(x);
    return (u + 0x7FFFu + ((u >> 16) & 1u)) >> 16;
}

#define LD8V(dst, src)                                                    \
    {                                                                     \
        float4 t0_ = *(const float4*)(src);                               \
        float4 t1_ = *(const float4*)((src) + 4);                         \
        dst[0] = (v2f){t0_.x, t0_.y}; dst[1] = (v2f){t0_.z, t0_.w};       \
        dst[2] = (v2f){t1_.x, t1_.y}; dst[3] = (v2f){t1_.z, t1_.w};       \
    }

// ---- compiler-opaque 16B load: cannot be sunk/flattened/spilled-around ----
__device__ __forceinline__ void asm_ld(u32x4& dst, const void* addr) {
    asm volatile("global_load_dwordx4 %0, %1, off" : "=&v"(dst) : "v"(addr));
}
// counted vmcnt wait + scheduling fence (rule #18)
#define VWAIT(N)                                                          \
    do {                                                                  \
        asm volatile("s_waitcnt vmcnt(" #N ")");                          \
        __builtin_amdgcn_sched_barrier(0);                                \
    } while (0)

// ---- build bf16 ew LUT (nearest-neighbor), packed 2 channels per u32 word ----
__global__ void k_lut(const float* __restrict__ deW, const float* __restrict__ deb,
                      const float* __restrict__ deg, const float* __restrict__ debe,
                      unsigned* __restrict__ lutp) {
    int e = blockIdx.x * 4 + (threadIdx.x >> 6);
    int lane = threadIdx.x & 63;
    int c0 = 2 * lane, c1 = 2 * lane + 1;
    float d = e * (DMAX_ / (KLUT_ - 1));
    float s0 = expf(-d), s1 = expf(-0.5f * d), s2 = expf(-0.25f * d);
    float a0 = s0 * deW[c0] + s1 * deW[H_ + c0] + s2 * deW[2 * H_ + c0] + deb[c0];
    float a1 = s0 * deW[c1] + s1 * deW[H_ + c1] + s2 * deW[2 * H_ + c1] + deb[c1];
    float v0 = a0 / (1.f + expf(-a0));
    float v1 = a1 / (1.f + expf(-a1));
    float sum = v0 + v1, ssq = v0 * v0 + v1 * v1;
#pragma unroll
    for (int mask = 1; mask < 64; mask <<= 1) {
        sum += __shfl_xor(sum, mask);
        ssq += __shfl_xor(ssq, mask);
    }
    float mu = sum * (1.f / H_);
    float var = ssq * (1.f / H_) - mu * mu;
    float rstd = 1.f / sqrtf(var + EPS_);
    float r0 = (v0 - mu) * rstd * deg[c0] + debe[c0];
    float r1 = (v1 - mu) * rstd * deg[c1] + debe[c1];
    lutp[e * (H_ / 2) + lane] = bfr(r0) | (bfr(r1) << 16);
}

// ---------------- x = emb[an]; pre = x@Wi + msg_b; prj(bf16) = x@Wj ----------------
__global__ void k_embed_gemm(const int* __restrict__ an, const float* __restrict__ emb,
                             const float* __restrict__ W, const float* __restrict__ b,
                             float* __restrict__ x, float* __restrict__ preb,
                             ushort16* __restrict__ prj) {
    int i = blockIdx.x;
    int t = threadIdx.x;               // 256 threads
    __shared__ float xr[H_];
    if (t < H_) {
        float xv = emb[an[i] * H_ + t];
        xr[t] = xv;
        x[i * H_ + t] = xv;
    }
    __syncthreads();
    int h = t & (H_ - 1);
    int off = (t >= H_) ? H_ : 0;
    float s = 0.f;
#pragma unroll 4
    for (int k = 0; k < H_; k += 4) {
        float4 xv = *(const float4*)&xr[k];
        s = fmaf(xv.x, W[(off + k) * H_ + h], s);
        s = fmaf(xv.y, W[(off + k + 1) * H_ + h], s);
        s = fmaf(xv.z, W[(off + k + 2) * H_ + h], s);
        s = fmaf(xv.w, W[(off + k + 3) * H_ + h], s);
    }
    if (t >= H_) prj[i * H_ + h] = (ushort16)bfr(s);
    else         preb[i * H_ + h] = s + b[h];
}

// ---- jof stream: LDS-held LUT byte offset for tile t, pair-slot p (+cb2 prefolded) ----
__device__ __forceinline__ int ldjof(const int* jinfo, int t, int p, int cb2) {
    return jinfo[(t << 5) + p] + cb2;
}

// ---- compute one j-tile from raw bf16x8 words: poly-silu + LN stats; accumulate ----
// all mul+add chains written as explicit FMA so the backend emits v_pk_fma_f32
// instead of pk_mul+pk_add pairs (no -ffast-math in harness flags).
__device__ __forceinline__ void cmp_step(u32x4 rl, u32x4 rp,
                                         const v2f (&pbv)[4],
                                         v2f (&acc1)[4], v2f (&acc2)[4]) {
    const v2f pc3 = {PC3_, PC3_}, pc2 = {PC2_, PC2_}, pc1 = {PC1_, PC1_},
              pc0 = {PC0_, PC0_}, half2 = {0.5f, 0.5f};
    v2f TM[4];
    v2f sum2 = {0.f, 0.f}, ssq2 = {0.f, 0.f};
#pragma unroll
    for (int k = 0; k < 4; ++k) {
        unsigned pw = rp[k];
        v2f tm = (v2f){__uint_as_float(pw << 16),
                       __uint_as_float(pw & 0xffff0000u)};
        v2f wv = pbv[k] + tm;
        v2f vc;
        vc.x = __builtin_amdgcn_fmed3f(wv.x, -4.0f, 4.0f);
        vc.y = __builtin_amdgcn_fmed3f(wv.y, -4.0f, 4.0f);
        v2f u = vc * vc;
        v2f pp = fma2(pc3, u, pc2);
        pp = fma2(pp, u, pc1);
        pp = fma2(pp, u, pc0);
        v2f sg = fma2(vc, pp, half2);   // sigmoid approx
        v2f vv = wv * sg;               // silu
        TM[k] = vv;
        sum2 += vv;
        ssq2 = fma2(vv, vv, ssq2);
    }
    float sum = rowreduce16(sum2.x + sum2.y);
    float ssq = rowreduce16(ssq2.x + ssq2.y);
    float mu = sum * (1.f / H_);
    float var = fmaf(ssq, 1.f / H_, -mu * mu);
    float rstd = __builtin_amdgcn_rsqf(var + EPS_);
    float c1 = -mu * rstd;
    v2f rstd2 = {rstd, rstd}, c12 = {c1, c1};
#pragma unroll
    for (int k = 0; k < 4; ++k) {
        unsigned lw = rl[k];
        v2f ew = (v2f){__uint_as_float(lw << 16),
                       __uint_as_float(lw & 0xffff0000u)};
        v2f t = fma2(TM[k], rstd2, c12);
        acc1[k] = fma2(t, ew, acc1[k]);
        acc2[k] += ew;
    }
}

// ---------------- pairwise kernel + fused update + next-level pre/prj ----------------
// block = row i, 512 threads = 8 waves; each 16-lane row owns one pair (i,j);
// lane q owns 8 contiguous channels [8q, 8q+8).
// launch_bounds: (512,8) spills (r9); 6 is the safe point.
// j-loop: 3-slot rotation with inline-asm loads + counted vmcnt(4) (T4 pattern).
__global__ __launch_bounds__(512, 6) void k_pair(
    const float* __restrict__ pos, const float* __restrict__ x,
    const float* __restrict__ prebR, const ushort16* __restrict__ prjR,
    const unsigned* __restrict__ lutp,
    const float* __restrict__ mgp, const float* __restrict__ mbep,
    const float* __restrict__ uW, const float* __restrict__ ub,
    const float* __restrict__ ug, const float* __restrict__ ube,
    const float* __restrict__ Wn, const float* __restrict__ bn,
    float* __restrict__ xout, float* __restrict__ lmean,
    float* __restrict__ prebW, ushort16* __restrict__ prjW) {
    const int i = blockIdx.x;
    const int tid = threadIdx.x;
    const int w = tid >> 6;
    const int lane = tid & 63;
    const int g = lane >> 4;
    const int q = lane & 15;
    const int p = w * 4 + g;           // 0..31: pair slot
    const int cb = q * 8;              // channel base
    const int cb2 = cb * 2;            // byte offset of channel base (bf16)

    __shared__ int jinfo[N_ + 96];     // NN lut row byte offset per j (+pad to jof(34))
    __shared__ float red[32][H_];
    __shared__ float msums[H_], xrow[H_], xs[H_];
    __shared__ float part[4][H_];
    __shared__ float r4[2][2];

    v2f pbv[4], acc1[4], acc2[4];
    LD8V(pbv, prebR + i * H_ + cb);
#pragma unroll
    for (int k = 0; k < 4; ++k) { acc1[k] = (v2f){0.f, 0.f}; acc2[k] = (v2f){0.f, 0.f}; }

    const float pix = pos[3 * i], piy = pos[3 * i + 1], piz = pos[3 * i + 2];
    for (int j = tid; j < N_; j += 512) {
        float dx = pix - pos[3 * j];
        float dy = piy - pos[3 * j + 1];
        float dz = piz - pos[3 * j + 2];
        float sq = fmaf(dx, dx, fmaf(dy, dy, dz * dz));
        float d = __builtin_amdgcn_sqrtf(sq);
        float tf = fminf(d * TSCALE_, TMAX_);
        int i0 = (int)(tf + 0.5f);     // nearest entry
        jinfo[j] = i0 * ROWB_;
    }
    if (tid < 96) jinfo[N_ + tid] = 0; // pad: dead jof over-reads land here
    if (tid < H_) xrow[tid] = x[i * H_ + tid];
    __syncthreads();
    // drain ALL tracked memory ops so SIInsertWaitcnts places no waits in the loop
    __builtin_amdgcn_s_waitcnt(0);

    // ---- 3-slot asm pipeline with counted vmcnt ----
    const char* prjRow = (const char*)prjR + p * ROWB_ + q * 16;   // tile t: +t*TILEB_
    const char* lutb = (const char*)lutp;
    int j0 = ldjof(jinfo, 0, p, cb2);
    int j1 = ldjof(jinfo, 1, p, cb2);
    int j2 = ldjof(jinfo, 2, p, cb2);
    u32x4 L0, P0, L1, P1, L2, P2;
    asm_ld(L0, lutb + j0); asm_ld(P0, prjRow);
    j0 = ldjof(jinfo, 3, p, cb2);
    asm_ld(L1, lutb + j1); asm_ld(P1, prjRow + 1 * TILEB_);
    j1 = ldjof(jinfo, 4, p, cb2);
    __builtin_amdgcn_sched_barrier(0);
    for (int t = 0; t < NT_ - 2; t += 3) {             // t = 0,3,...,27
        asm_ld(L2, lutb + j2); asm_ld(P2, prjRow + (t + 2) * TILEB_);
        j2 = ldjof(jinfo, t + 5, p, cb2);
        VWAIT(4);
        cmp_step(L0, P0, pbv, acc1, acc2);             // tile t
        __builtin_amdgcn_sched_barrier(0);
        asm_ld(L0, lutb + j0); asm_ld(P0, prjRow + (t + 3) * TILEB_);
        j0 = ldjof(jinfo, t + 6, p, cb2);
        VWAIT(4);
        cmp_step(L1, P1, pbv, acc1, acc2);             // tile t+1
        __builtin_amdgcn_sched_barrier(0);
        asm_ld(L1, lutb + j1); asm_ld(P1, prjRow + (t + 4) * TILEB_);
        j1 = ldjof(jinfo, t + 7, p, cb2);              // t=27 -> jof(34): pad (dead)
        VWAIT(4);
        cmp_step(L2, P2, pbv, acc1, acc2);             // tile t+2
        __builtin_amdgcn_sched_barrier(0);
    }
    // after loop: L0/P0 = tile 30 in flight, L1/P1 = tile 31 in flight
    VWAIT(2);
    cmp_step(L0, P0, pbv, acc1, acc2);                 // tile 30
    VWAIT(0);
    cmp_step(L1, P1, pbv, acc1, acc2);                 // tile 31

    // ---- apply g/be and combine 32 pair-slot partials -> msum (block-local) ----
    v2f mgv[4], mbev[4], accv[4];
    LD8V(mgv, mgp + cb);
    LD8V(mbev, mbep + cb);
#pragma unroll
    for (int k = 0; k < 4; ++k)
        accv[k] = fma2(mgv[k], acc1[k], mbev[k] * acc2[k]);
    *(float4*)&red[p][cb] = make_float4(accv[0].x, accv[0].y, accv[1].x, accv[1].y);
    *(float4*)&red[p][cb + 4] = make_float4(accv[2].x, accv[2].y, accv[3].x, accv[3].y);
    __syncthreads();
    if (tid < H_) {
        float s = 0.f;
#pragma unroll
        for (int pp = 0; pp < 32; ++pp) s += red[pp][tid];
        msums[tid] = s;
    }
    __syncthreads();

    // ---- fused update: x += LN(silu([x,msum]@uW+ub)); lmean += x ----
    int h = tid & (H_ - 1);
    int seg = tid >> 7;                // 4-way K split
    const float* src = (seg == 0) ? xrow : (seg == 1) ? xrow + 64
                     : (seg == 2) ? msums : msums + 64;
    const float* Wp = uW + (seg * 64) * H_ + h;
    float s2 = 0.f;
#pragma unroll 4
    for (int k = 0; k < 64; k += 4) {
        float4 uv = *(const float4*)&src[k];
        s2 = fmaf(uv.x, Wp[(k + 0) * H_], s2);
        s2 = fmaf(uv.y, Wp[(k + 1) * H_], s2);
        s2 = fmaf(uv.z, Wp[(k + 2) * H_], s2);
        s2 = fmaf(uv.w, Wp[(k + 3) * H_], s2);
    }
    part[seg][h] = s2;
    __syncthreads();
    float v = 0.f;
    if (tid < H_) {
        float sv = part[0][tid] + part[1][tid] + part[2][tid] + part[3][tid] + ub[tid];
        v = sv * fsig(sv);
    }
    float sum = v, ssq = v * v;
#pragma unroll
    for (int mask = 1; mask < 64; mask <<= 1) {
        sum += __shfl_xor(sum, mask);
        ssq += __shfl_xor(ssq, mask);
    }
    if (tid < H_ && (tid & 63) == 0) { r4[tid >> 6][0] = sum; r4[tid >> 6][1] = ssq; }
    __syncthreads();
    if (tid < H_) {
        sum = r4[0][0] + r4[1][0];
        ssq = r4[0][1] + r4[1][1];
        float mu = sum * (1.f / H_);
        float var = fmaf(ssq, 1.f / H_, -mu * mu);
        float rstd = rsqrtf(var + EPS_);
        float xn = xrow[tid] + fmaf((v - mu) * rstd, ug[tid], ube[tid]);
        xs[tid] = xn;
        xout[i * H_ + tid] = xn;
        atomicAdd(&lmean[tid], xn);
    }

    // ---- fused next-level pre/prj = xs @ Wn (+bn), into ping-pong buffers ----
    if (Wn) {
        __syncthreads();               // xs ready; also all part reads done
        int which = tid >> 8;          // 0 = pre, 1 = prj
        int kh = (tid >> 7) & 1;       // K half
        const float* Wp2 = Wn + (which * H_ + kh * 64) * H_ + h;
        const float* xsrc = xs + kh * 64;
        float s3 = 0.f;
#pragma unroll 4
        for (int k = 0; k < 64; k += 4) {
            float4 xv = *(const float4*)&xsrc[k];
            s3 = fmaf(xv.x, Wp2[(k + 0) * H_], s3);
            s3 = fmaf(xv.y, Wp2[(k + 1) * H_], s3);
            s3 = fmaf(xv.z, Wp2[(k + 2) * H_], s3);
            s3 = fmaf(xv.w, Wp2[(k + 3) * H_], s3);
        }
        part[(which << 1) | kh][h] = s3;
        __syncthreads();
        if (tid < 256) {
            int wh = tid >> 7, h3 = tid & 127;
            float val = part[wh * 2][h3] + part[wh * 2 + 1][h3];
            if (wh) prjW[i * H_ + h3] = (ushort16)bfr(val);
            else    prebW[i * H_ + h3] = val + bn[h3];
        }
    }
}

// ---------------- out = LN(combined @ fp_W + fp_b) ----------------
__global__ void k_final(const float* __restrict__ lmean, const float* __restrict__ fpW,
                        const float* __restrict__ fpb, const float* __restrict__ fpg,
                        const float* __restrict__ fpbe, float* __restrict__ out) {
    int t = threadIdx.x;               // 256 threads
    __shared__ float comb[L_ * H_];
    comb[t] = lmean[t] * (1.f / N_);
    if (t < L_ * H_ - D_) comb[D_ + t] = lmean[D_ + t] * (1.f / N_);
    __syncthreads();
    float s = fpb[t];
#pragma unroll 8
    for (int k = 0; k < L_ * H_; ++k)
        s = fmaf(comb[k], fpW[k * D_ + t], s);
    float sum = s, ssq = s * s;
#pragma unroll
    for (int mask = 1; mask < 64; mask <<= 1) {
        sum += __shfl_xor(sum, mask);
        ssq += __shfl_xor(ssq, mask);
    }
    __shared__ float r4[4][2];
    int wv = t >> 6;
    if ((t & 63) == 0) { r4[wv][0] = sum; r4[wv][1] = ssq; }
    __syncthreads();
    sum = r4[0][0] + r4[1][0] + r4[2][0] + r4[3][0];
    ssq = r4[0][1] + r4[1][1] + r4[2][1] + r4[3][1];
    float mu = sum * (1.f / D_);
    float var = fmaf(ssq, 1.f / D_, -mu * mu);
    float rstd = rsqrtf(var + EPS_);
    out[t] = fmaf((s - mu) * rstd, fpg[t], fpbe[t]);
}

extern "C" void kernel_launch(void* const* d_in, const int* in_sizes, int n_in,
                              void* d_out, int out_size, void* d_ws, size_t ws_size,
                              hipStream_t stream) {
    const int*   an    = (const int*)d_in[0];
    const float* pos   = (const float*)d_in[1];
    const float* emb   = (const float*)d_in[2];
    const float* deW   = (const float*)d_in[3];
    const float* deb   = (const float*)d_in[4];
    const float* deg   = (const float*)d_in[5];
    const float* debe  = (const float*)d_in[6];
    const float* msgW  = (const float*)d_in[7];
    const float* msgb  = (const float*)d_in[8];
    const float* msgg  = (const float*)d_in[9];
    const float* msgbe = (const float*)d_in[10];
    const float* updW  = (const float*)d_in[11];
    const float* updb  = (const float*)d_in[12];
    const float* updg  = (const float*)d_in[13];
    const float* updbe = (const float*)d_in[14];
    const float* fpW   = (const float*)d_in[15];
    const float* fpb   = (const float*)d_in[16];
    const float* fpg   = (const float*)d_in[17];
    const float* fpbe  = (const float*)d_in[18];
    float* out = (float*)d_out;

    float* ws    = (float*)d_ws;
    float* x     = ws;                               // N*H f32
    float* prebA = x + N_ * H_;                      // N*H f32
    float* prebB = prebA + N_ * H_;                  // N*H f32
    ushort16* prjA = (ushort16*)(prebB + N_ * H_);   // N*H bf16
    ushort16* prjB = prjA + N_ * H_;                 // N*H bf16
    float* lmean = (float*)(prjB + N_ * H_);         // L*H f32
    unsigned* lutp = (unsigned*)(lmean + L_ * H_);   // KLUT * H/2 words (2 MB)

    hipMemsetAsync(lmean, 0, L_ * H_ * sizeof(float), stream);
    k_lut<<<KLUT_ / 4, 256, 0, stream>>>(deW, deb, deg, debe, lutp);
    k_embed_gemm<<<N_, 256, 0, stream>>>(an, emb, msgW, msgb, x, prebA, prjA);
    for (int lvl = 0; lvl < L_; ++lvl) {
        const float* pR  = (lvl & 1) ? prebB : prebA;
        const ushort16* prR = (lvl & 1) ? prjB : prjA;
        float* pW  = (lvl & 1) ? prebA : prebB;
        ushort16* prW = (lvl & 1) ? prjA : prjB;
        const float* Wn = (lvl < L_ - 1) ? msgW + (lvl + 1) * 2 * H_ * H_ : nullptr;
        const float* bn = (lvl < L_ - 1) ? msgb + (lvl + 1) * H_ : nullptr;
        k_pair<<<N_, 512, 0, stream>>>(pos, x, pR, prR, lutp,
                                       msgg + lvl * H_, msgbe + lvl * H_,
                                       updW + lvl * 2 * H_ * H_, updb + lvl * H_,
                                       updg + lvl * H_, updbe + lvl * H_,
                                       Wn, bn, x, lmean + lvl * H_, pW, prW);
    }
    k_final<<<1, D_, 0, stream>>>(lmean, fpW, fpb, fpg, fpbe, out);
}